// Round 6
// baseline (147.274 us; speedup 1.0000x reference)
//
#include <hip/hip_runtime.h>

// QDPPMixer, R6: G=4 cooperative gather, G=1 compute.
// R5 lesson: at G=4 the serial per-element work (index calc, M-build, LU, log)
// amortizes over only 16 elements/wave (~19 instr/elem of the ~48 total).
// R6: one THREAD per element. Gather runs in 4 rounds; in round R each quad
// DPP-broadcasts lane R's row offsets, gathers that element's 8 rows with the
// R3 pattern (16 lines/instr, each line fetched once), computes partial Gram,
// DPP-butterfly reduces, and lane R keeps it (cndmask). After 4 rounds every
// lane holds its own element's Gram; M-build + no-pivot LU + log run at G=1
// (64 elements/wave). Algebra from R5: normalize folded out via
// det(M) = det(Atil)/prod(g_ii), Atil off-diag = relu(g_ij),
// Atil_ii = g_ii*(1 + 0.1*nz_i + eps).

constexpr int   NA         = 8;
constexpr float Q_MIN      = -10.0f;
constexpr float Q_MAX      = 10.0f;
constexpr float NOISE_COEF = 0.1f;
constexpr float EPS        = 1e-8f;

#define P(i, j) ((i) * 8 + (j) - (i) * ((i) + 1) / 2)   // upper-tri flat index, i<=j

// butterfly partial: add value from lane^1 / lane^2 within quad (pure VALU DPP)
__device__ __forceinline__ float dpp_add1(float x) {
    return x + __builtin_bit_cast(float,
        __builtin_amdgcn_mov_dpp(__builtin_bit_cast(int, x), 0xB1, 0xF, 0xF, true));
}
__device__ __forceinline__ float dpp_add2(float x) {
    return x + __builtin_bit_cast(float,
        __builtin_amdgcn_mov_dpp(__builtin_bit_cast(int, x), 0x4E, 0xF, 0xF, true));
}
// broadcast lane R of each quad to the whole quad: quad_perm [R,R,R,R]
template<int R>
__device__ __forceinline__ int qbcast(int x) {
    return __builtin_amdgcn_mov_dpp(x, R * 0x55, 0xF, 0xF, true);
}

template<int R>
__device__ __forceinline__ void do_round(const float* __restrict__ W,
                                         const int off[8], int lb, int lanesel,
                                         float gm[36])
{
    // offsets of this round's element (lane R of the quad), broadcast to quad
    int offr[8];
    #pragma unroll
    for (int i = 0; i < 8; i++) offr[i] = qbcast<R>(off[i]);

    float p[36];
    {   // chunk A: dims [4l, 4l+4)
        float4 v[8];
        #pragma unroll
        for (int i = 0; i < 8; i++)
            v[i] = *reinterpret_cast<const float4*>(W + offr[i] + lb);
        #pragma unroll
        for (int i = 0; i < 8; i++) {
            #pragma unroll
            for (int j = i; j < 8; j++) {
                float a = v[i].x * v[j].x;
                a = fmaf(v[i].y, v[j].y, a);
                a = fmaf(v[i].z, v[j].z, a);
                a = fmaf(v[i].w, v[j].w, a);
                p[P(i, j)] = a;
            }
        }
    }
    {   // chunk B: dims [16+4l, 16+4l+4)
        float4 v[8];
        #pragma unroll
        for (int i = 0; i < 8; i++)
            v[i] = *reinterpret_cast<const float4*>(W + offr[i] + 16 + lb);
        #pragma unroll
        for (int i = 0; i < 8; i++) {
            #pragma unroll
            for (int j = i; j < 8; j++) {
                float a = p[P(i, j)];
                a = fmaf(v[i].x, v[j].x, a);
                a = fmaf(v[i].y, v[j].y, a);
                a = fmaf(v[i].z, v[j].z, a);
                a = fmaf(v[i].w, v[j].w, a);
                p[P(i, j)] = a;
            }
        }
    }
    // butterfly reduce across quad; lane R keeps its element's Gram
    bool keep = (lanesel == R);
    #pragma unroll
    for (int k = 0; k < 36; k++) {
        float red = dpp_add2(dpp_add1(p[k]));
        gm[k] = keep ? red : gm[k];
    }
}

__global__ __launch_bounds__(256, 4) void qdpp_kernel(
    const float* __restrict__ agent_qs,
    const int*   __restrict__ states,
    const int*   __restrict__ actions,
    const float* __restrict__ noise,
    const float* __restrict__ W,      // (8000, 32) fp32, rows 128B-aligned
    float*       __restrict__ out,
    int bs)
{
    int tid = blockIdx.x * blockDim.x + threadIdx.x;
    if (tid >= bs) return;            // grid is exact; kept for safety (bs % 4 == 0)
    size_t base = (size_t)tid * NA;

    // ---- MY element's indices (fully coalesced: lane k -> element k) ----
    int4 s0 = *reinterpret_cast<const int4*>(states + base);
    int4 s1 = *reinterpret_cast<const int4*>(states + base + 4);
    int4 a0 = *reinterpret_cast<const int4*>(actions + base);
    int4 a1 = *reinterpret_cast<const int4*>(actions + base + 4);

    int off[8];
    off[0] = (s0.x * 10 + a0.x        ) * 32;
    off[1] = (s0.y * 10 + a0.y + 1000 ) * 32;
    off[2] = (s0.z * 10 + a0.z + 2000 ) * 32;
    off[3] = (s0.w * 10 + a0.w + 3000 ) * 32;
    off[4] = (s1.x * 10 + a1.x + 4000 ) * 32;
    off[5] = (s1.y * 10 + a1.y + 5000 ) * 32;
    off[6] = (s1.z * 10 + a1.z + 6000 ) * 32;
    off[7] = (s1.w * 10 + a1.w + 7000 ) * 32;

    int lanesel = threadIdx.x & 3;
    int lb = 4 * lanesel;             // this lane's dim slice within the quad

    // ---- 4 gather rounds: quad q round R handles element 4q+R ----
    float gm[36];
    #pragma unroll
    for (int k = 0; k < 36; k++) gm[k] = 0.0f;

    do_round<0>(W, off, lb, lanesel, gm);
    do_round<1>(W, off, lb, lanesel, gm);
    do_round<2>(W, off, lb, lanesel, gm);
    do_round<3>(W, off, lb, lanesel, gm);

    // ---- G=1 epilogue: streaming loads (coalesced), qsum ----
    float4 qa = *reinterpret_cast<const float4*>(agent_qs + base);
    float4 qv = *reinterpret_cast<const float4*>(agent_qs + base + 4);
    float4 n0 = *reinterpret_cast<const float4*>(noise + base);
    float4 n1 = *reinterpret_cast<const float4*>(noise + base + 4);

    float qsum = fminf(fmaxf(qa.x, Q_MIN), Q_MAX) + fminf(fmaxf(qa.y, Q_MIN), Q_MAX)
               + fminf(fmaxf(qa.z, Q_MIN), Q_MAX) + fminf(fmaxf(qa.w, Q_MIN), Q_MAX)
               + fminf(fmaxf(qv.x, Q_MIN), Q_MAX) + fminf(fmaxf(qv.y, Q_MIN), Q_MAX)
               + fminf(fmaxf(qv.z, Q_MIN), Q_MAX) + fminf(fmaxf(qv.w, Q_MIN), Q_MAX);

    float nz[8] = {n0.x, n0.y, n0.z, n0.w, n1.x, n1.y, n1.z, n1.w};

    // ---- Atil: off-diag = relu(g_ij), diag = g_ii*(1 + 0.1*nz_i + eps) ----
    float m[8][8];
    float pgii = 1.0f;
    #pragma unroll
    for (int i = 0; i < 8; i++) {
        float gii = gm[P(i, i)];
        pgii *= gii;
        m[i][i] = gii * fmaf(NOISE_COEF, nz[i], 1.0f + EPS);
        #pragma unroll
        for (int j = i + 1; j < 8; j++) {
            float r = fmaxf(gm[P(i, j)], 0.0f);
            m[i][j] = r;
            m[j][i] = r;
        }
    }

    // ---- det via unrolled no-pivot LU (diag-dominant in practice) ----
    float det = 1.0f;
    #pragma unroll
    for (int k = 0; k < 8; k++) {
        float piv = m[k][k];
        det *= piv;
        float ip = __builtin_amdgcn_rcpf(piv);
        #pragma unroll
        for (int i = k + 1; i < 8; i++) {
            float f = m[i][k] * ip;
            #pragma unroll
            for (int j = k + 1; j < 8; j++)
                m[i][j] = fmaf(-f, m[k][j], m[i][j]);
        }
    }

    // det(M) = det(Atil)/prod(g_ii); out = qsum + log(det(M) + 1e-8)
    float detM = det * __builtin_amdgcn_rcpf(pgii);
    out[tid] = qsum + __logf(detM + EPS);
}

extern "C" void kernel_launch(void* const* d_in, const int* in_sizes, int n_in,
                              void* d_out, int out_size, void* d_ws, size_t ws_size,
                              hipStream_t stream) {
    const float* agent_qs = (const float*)d_in[0];
    const int*   states   = (const int*)d_in[1];
    const int*   actions  = (const int*)d_in[2];
    const float* noise    = (const float*)d_in[3];
    const float* W        = (const float*)d_in[4];
    float*       out      = (float*)d_out;

    int bs = in_sizes[0] / NA;        // 262144
    const int block = 256;
    int grid = (bs + block - 1) / block;   // one thread per element
    qdpp_kernel<<<grid, block, 0, stream>>>(agent_qs, states, actions, noise, W, out, bs);
}

// Round 7
// 96.431 us; speedup vs baseline: 1.5272x; 1.5272x over previous
//
#include <hip/hip_runtime.h>
#include <hip/hip_fp16.h>

// QDPPMixer, R7: R5 structure (G=4 gather, replicated epilogue — R6's G=1
// compute spilled: WRITE_SIZE 116 MB of scratch) + fp16 table.
// Lane-request wall: every fp32 variant converges to ~1 lane-req/cyc/CU in the
// TA (R5: 16.8M reqs ~= 27us floor ~= measured 32us). fp32 needs 64 lane-reqs
// per element (1KB @ 16B/lane). Converting W to fp16 (once per call, into d_ws)
// makes a row 64B: ONE gather instr per row (quad of 4 lanes x 16B), i.e.
// 32 lane-reqs + 8 unique lines per element — the memory side halves.
// Gram via v_dot2_f32_f16 (fp32 accum). Algebra from R5: normalize folded out,
// det(M) = det(Atil)/prod(g_ii). fp16 quantization -> logdet err ~1e-2 << 0.255.

constexpr int   NA         = 8;
constexpr float Q_MIN      = -10.0f;
constexpr float Q_MAX      = 10.0f;
constexpr float NOISE_COEF = 0.1f;
constexpr float EPS        = 1e-8f;

typedef _Float16 half2_t __attribute__((ext_vector_type(2)));

__device__ __forceinline__ float dot2(half2_t a, half2_t b, float c) {
#if __has_builtin(__builtin_amdgcn_fdot2)
    return __builtin_amdgcn_fdot2(a, b, c, false);
#else
    return fmaf((float)a.x, (float)b.x, fmaf((float)a.y, (float)b.y, c));
#endif
}

// quad butterfly adds (pure VALU DPP)
__device__ __forceinline__ float qadd1(float x) {
    return x + __builtin_bit_cast(float,
        __builtin_amdgcn_mov_dpp(__builtin_bit_cast(int, x), 0xB1, 0xF, 0xF, true));
}
__device__ __forceinline__ float qadd2(float x) {
    return x + __builtin_bit_cast(float,
        __builtin_amdgcn_mov_dpp(__builtin_bit_cast(int, x), 0x4E, 0xF, 0xF, true));
}

// ---- convert W (8000x32 fp32) -> fp16, 4 floats/thread ----
__global__ __launch_bounds__(256) void convert_kernel(
    const float* __restrict__ W, __half* __restrict__ W16, int n4)
{
    int t = blockIdx.x * blockDim.x + threadIdx.x;
    if (t >= n4) return;
    float4 v = reinterpret_cast<const float4*>(W)[t];
    ushort4 h;
    h.x = __half_as_ushort(__float2half(v.x));
    h.y = __half_as_ushort(__float2half(v.y));
    h.z = __half_as_ushort(__float2half(v.z));
    h.w = __half_as_ushort(__float2half(v.w));
    reinterpret_cast<ushort4*>(W16)[t] = h;
}

__global__ __launch_bounds__(256, 4) void qdpp_kernel(
    const float* __restrict__ agent_qs,
    const int*   __restrict__ states,
    const int*   __restrict__ actions,
    const float* __restrict__ noise,
    const __half* __restrict__ W16,   // (8000, 32) fp16, rows 64B
    float*       __restrict__ out,
    int bs)
{
    int tid = blockIdx.x * blockDim.x + threadIdx.x;
    int e = tid >> 2;        // element index (4 lanes per element)
    int l = tid & 3;         // lane in quad: halves [8l, 8l+8) of each row
    if (e >= bs) return;
    size_t base = (size_t)e * NA;

    // ---- indices (quad-broadcast loads) ----
    int4 s0 = *reinterpret_cast<const int4*>(states + base);
    int4 s1 = *reinterpret_cast<const int4*>(states + base + 4);
    int4 a0 = *reinterpret_cast<const int4*>(actions + base);
    int4 a1 = *reinterpret_cast<const int4*>(actions + base + 4);

    int lb = 8 * l;          // half-element offset within row
    int off[8];
    off[0] = (s0.x * 10 + a0.x        ) * 32 + lb;
    off[1] = (s0.y * 10 + a0.y + 1000 ) * 32 + lb;
    off[2] = (s0.z * 10 + a0.z + 2000 ) * 32 + lb;
    off[3] = (s0.w * 10 + a0.w + 3000 ) * 32 + lb;
    off[4] = (s1.x * 10 + a1.x + 4000 ) * 32 + lb;
    off[5] = (s1.y * 10 + a1.y + 5000 ) * 32 + lb;
    off[6] = (s1.z * 10 + a1.z + 6000 ) * 32 + lb;
    off[7] = (s1.w * 10 + a1.w + 7000 ) * 32 + lb;

    // ---- gather: ONE 16B instr per row; quad covers the whole 64B row ----
    uint4 raw[8];
    #pragma unroll
    for (int i = 0; i < 8; i++)
        raw[i] = *reinterpret_cast<const uint4*>(W16 + off[i]);

    // ---- streaming loads issued while gathers are in flight ----
    float4 qa = *reinterpret_cast<const float4*>(agent_qs + base);
    float4 qb = *reinterpret_cast<const float4*>(agent_qs + base + 4);
    float4 n0 = *reinterpret_cast<const float4*>(noise + base);
    float4 n1 = *reinterpret_cast<const float4*>(noise + base + 4);

    half2_t h[8][4];
    #pragma unroll
    for (int i = 0; i < 8; i++) {
        h[i][0] = __builtin_bit_cast(half2_t, raw[i].x);
        h[i][1] = __builtin_bit_cast(half2_t, raw[i].y);
        h[i][2] = __builtin_bit_cast(half2_t, raw[i].z);
        h[i][3] = __builtin_bit_cast(half2_t, raw[i].w);
    }

    // ---- per-lane partial Gram (this lane's 8 of 32 dims), v_dot2 chains ----
    float g[8][8];
    #pragma unroll
    for (int i = 0; i < 8; i++) {
        #pragma unroll
        for (int j = i; j < 8; j++) {
            float acc = dot2(h[i][0], h[j][0], 0.0f);
            acc = dot2(h[i][1], h[j][1], acc);
            acc = dot2(h[i][2], h[j][2], acc);
            acc = dot2(h[i][3], h[j][3], acc);
            g[i][j] = acc;
        }
    }

    // ---- quad butterfly reduce (pure VALU DPP) ----
    #pragma unroll
    for (int i = 0; i < 8; i++)
        #pragma unroll
        for (int j = i; j < 8; j++)
            g[i][j] = qadd2(qadd1(g[i][j]));

    // ---- Q-sum with clip ----
    float qsum = fminf(fmaxf(qa.x, Q_MIN), Q_MAX) + fminf(fmaxf(qa.y, Q_MIN), Q_MAX)
               + fminf(fmaxf(qa.z, Q_MIN), Q_MAX) + fminf(fmaxf(qa.w, Q_MIN), Q_MAX)
               + fminf(fmaxf(qb.x, Q_MIN), Q_MAX) + fminf(fmaxf(qb.y, Q_MIN), Q_MAX)
               + fminf(fmaxf(qb.z, Q_MIN), Q_MAX) + fminf(fmaxf(qb.w, Q_MIN), Q_MAX);

    float nz[8] = {n0.x, n0.y, n0.z, n0.w, n1.x, n1.y, n1.z, n1.w};

    // ---- Atil: off-diag = relu(g_ij), diag = g_ii*(1 + 0.1*nz_i + eps) ----
    float m[8][8];
    float pgii = 1.0f;
    #pragma unroll
    for (int i = 0; i < 8; i++) {
        pgii *= g[i][i];
        #pragma unroll
        for (int j = 0; j < 8; j++) {
            if (i == j) {
                m[i][i] = g[i][i] * fmaf(NOISE_COEF, nz[i], 1.0f + EPS);
            } else {
                float gij = (j > i) ? g[i][j] : g[j][i];   // compile-time select
                m[i][j] = fmaxf(gij, 0.0f);
            }
        }
    }

    // ---- det via unrolled no-pivot LU (diag-dominant in practice) ----
    float det = 1.0f;
    #pragma unroll
    for (int k = 0; k < 8; k++) {
        float p = m[k][k];
        det *= p;
        float ip = __builtin_amdgcn_rcpf(p);
        #pragma unroll
        for (int i = k + 1; i < 8; i++) {
            float f = m[i][k] * ip;
            #pragma unroll
            for (int j = k + 1; j < 8; j++)
                m[i][j] = fmaf(-f, m[k][j], m[i][j]);
        }
    }

    // det(M) = det(Atil)/prod(g_ii); out = qsum + log(det(M) + 1e-8)
    float detM = det * __builtin_amdgcn_rcpf(pgii);
    if (l == 0)
        out[e] = qsum + __logf(detM + EPS);
}

extern "C" void kernel_launch(void* const* d_in, const int* in_sizes, int n_in,
                              void* d_out, int out_size, void* d_ws, size_t ws_size,
                              hipStream_t stream) {
    const float* agent_qs = (const float*)d_in[0];
    const int*   states   = (const int*)d_in[1];
    const int*   actions  = (const int*)d_in[2];
    const float* noise    = (const float*)d_in[3];
    const float* W        = (const float*)d_in[4];
    float*       out      = (float*)d_out;
    __half*      W16      = (__half*)d_ws;          // 256000 halves = 512 KB

    int wn = in_sizes[4];             // 256000 floats
    int n4 = wn / 4;
    convert_kernel<<<(n4 + 255) / 256, 256, 0, stream>>>(W, W16, n4);

    int bs = in_sizes[0] / NA;            // 262144
    const int block = 256;
    long long total = (long long)bs * 4;  // 4 lanes per element
    int grid = (int)((total + block - 1) / block);
    qdpp_kernel<<<grid, block, 0, stream>>>(agent_qs, states, actions, noise, W16, out, bs);
}